// Round 7
// baseline (290.259 us; speedup 1.0000x reference)
//
#include <hip/hip_runtime.h>
#include <hip/hip_bf16.h>

// Problem constants
#define BB 4
#define HH 64
#define WW 64
#define LL 4096           // HH*WW
#define DM 192            // D_MODEL
#define DI 384            // D_INNER
#define NS 16             // D_STATE
#define RK 12             // DT_RANK
#define NC 128            // number of scan chunks
#define CH 32             // chunk length (NC*CH == LL)
#define ROWS 16384        // BB*LL
#define XDS 64            // xdbl row stride (44 cols padded to 64)
#define LOG2E 1.44269504f

typedef __bf16 bf16x8 __attribute__((ext_vector_type(8)));
typedef float  f32x4  __attribute__((ext_vector_type(4)));

#if defined(__has_builtin)
#if __has_builtin(__builtin_amdgcn_exp2f)
#define fexp2(x) __builtin_amdgcn_exp2f(x)
#else
#define fexp2(x) exp2f(x)
#endif
#else
#define fexp2(x) exp2f(x)
#endif

__device__ __forceinline__ float fsilu(float x) {
    return x / (1.0f + __expf(-x));
}

// f32 -> bf16 (RNE)
__device__ __forceinline__ unsigned short f2bf(float f) {
    unsigned int u = __float_as_uint(f);
    unsigned int r = (u + 0x7fffu + ((u >> 16) & 1u)) >> 16;
    return (unsigned short)r;
}

// ---------------------------------------------------------------------------
// Vectorized f32 -> bf16 convert (n multiple of 4)
// ---------------------------------------------------------------------------
__global__ __launch_bounds__(256) void f32_to_bf16_vec(
    const float* __restrict__ src, unsigned short* __restrict__ dst, int n4)
{
    int i = blockIdx.x * 256 + threadIdx.x;
    if (i < n4) {
        float4 v = ((const float4*)src)[i];
        ((ushort4*)dst)[i] = make_ushort4(f2bf(v.x), f2bf(v.y), f2bf(v.z), f2bf(v.w));
    }
}

// ---------------------------------------------------------------------------
// Build transposed bf16 weight: src (K x Nsrc f32) -> dst (Nrows x K bf16),
// rows n >= Nsrc are zero (padding).
// ---------------------------------------------------------------------------
__global__ __launch_bounds__(256) void build_bt(
    const float* __restrict__ src, unsigned short* __restrict__ dst,
    int K, int Nsrc, int Nrows)
{
    int idx = blockIdx.x * 256 + threadIdx.x;
    if (idx >= Nrows * K) return;
    int n = idx / K, k = idx % K;
    dst[idx] = (n < Nsrc) ? f2bf(src[k * Nsrc + n]) : (unsigned short)0;
}

// ---------------------------------------------------------------------------
// bf16 MFMA GEMM: C(MxN f32) = A(MxK bf16) * BT^T (BT is N x K bf16).
// 64x64 tile, BK=32. 256 thr = 4 waves (2x2), each wave 32x32 via 2x2
// mfma_f32_16x16x32_bf16 fragments. LDS row stride 80B (2-way bank alias).
// ---------------------------------------------------------------------------
template<bool SPLIT>
__global__ __launch_bounds__(256) void gemm_bf16_mfma(
    const unsigned short* __restrict__ A, const unsigned short* __restrict__ BT,
    float* __restrict__ C0, float* __restrict__ C1,
    int M, int N, int K, int halfN)
{
    __shared__ __align__(16) char lds[64 * 80 * 2];
    char* As = lds;
    char* Bs = lds + 64 * 80;
    const int tid = threadIdx.x;
    const int w = tid >> 6, lane = tid & 63;
    const int wm = w >> 1, wn = w & 1;
    const int row0 = blockIdx.x * 64, col0 = blockIdx.y * 64;
    const int r = tid >> 2, cch = tid & 3;
    const int l15 = lane & 15, k8 = lane >> 4;

    f32x4 acc[2][2] = {};
    for (int k0 = 0; k0 < K; k0 += 32) {
        *(float4*)(As + r * 80 + cch * 16) =
            *(const float4*)(A + (size_t)(row0 + r) * K + k0 + cch * 8);
        *(float4*)(Bs + r * 80 + cch * 16) =
            *(const float4*)(BT + (size_t)(col0 + r) * K + k0 + cch * 8);
        __syncthreads();
        bf16x8 a0 = *(const bf16x8*)(As + (wm * 32 +      l15) * 80 + k8 * 16);
        bf16x8 a1 = *(const bf16x8*)(As + (wm * 32 + 16 + l15) * 80 + k8 * 16);
        bf16x8 b0 = *(const bf16x8*)(Bs + (wn * 32 +      l15) * 80 + k8 * 16);
        bf16x8 b1 = *(const bf16x8*)(Bs + (wn * 32 + 16 + l15) * 80 + k8 * 16);
        acc[0][0] = __builtin_amdgcn_mfma_f32_16x16x32_bf16(a0, b0, acc[0][0], 0, 0, 0);
        acc[0][1] = __builtin_amdgcn_mfma_f32_16x16x32_bf16(a0, b1, acc[0][1], 0, 0, 0);
        acc[1][0] = __builtin_amdgcn_mfma_f32_16x16x32_bf16(a1, b0, acc[1][0], 0, 0, 0);
        acc[1][1] = __builtin_amdgcn_mfma_f32_16x16x32_bf16(a1, b1, acc[1][1], 0, 0, 0);
        __syncthreads();
    }

    float* Cw;
    int cbase, cstride;
    if (SPLIT) {
        cstride = halfN;
        if (col0 < halfN) { Cw = C0; cbase = col0; }
        else              { Cw = C1; cbase = col0 - halfN; }
    } else {
        Cw = C0; cbase = col0; cstride = N;
    }
    #pragma unroll
    for (int fm = 0; fm < 2; ++fm)
        #pragma unroll
        for (int fn = 0; fn < 2; ++fn)
            #pragma unroll
            for (int reg = 0; reg < 4; ++reg) {
                int row = row0 + wm * 32 + fm * 16 + k8 * 4 + reg;
                int col = cbase + wn * 32 + fn * 16 + l15;
                Cw[(size_t)row * cstride + col] = acc[fm][fn][reg];
            }
}

// ---------------------------------------------------------------------------
// Depthwise 3x3 conv (channel-last), bias + SiLU -> u (f32) + u_bf (bf16)
// ---------------------------------------------------------------------------
__global__ __launch_bounds__(256) void conv_dw_silu(
    const float* __restrict__ xi, const float* __restrict__ conv_w,
    const float* __restrict__ conv_b, float* __restrict__ u,
    unsigned short* __restrict__ u_bf)
{
    int idx = blockIdx.x * 256 + threadIdx.x;   // total BB*HH*WW*96
    int c4 = idx % 96;
    int rest = idx / 96;
    int w = rest % WW; rest /= WW;
    int h = rest % HH;
    int b = rest / HH;
    int c = c4 * 4;

    float wgt[4][9];
    #pragma unroll
    for (int q = 0; q < 4; ++q)
        #pragma unroll
        for (int t = 0; t < 9; ++t)
            wgt[q][t] = conv_w[(c + q) * 9 + t];

    float4 acc = *(const float4*)&conv_b[c];
    #pragma unroll
    for (int kh = 0; kh < 3; ++kh) {
        int hh = h + kh - 1;
        if ((unsigned)hh >= HH) continue;
        #pragma unroll
        for (int kw = 0; kw < 3; ++kw) {
            int ww = w + kw - 1;
            if ((unsigned)ww >= WW) continue;
            const float4 xv = *(const float4*)&xi[(((size_t)(b * HH + hh)) * WW + ww) * DI + c];
            int t = kh * 3 + kw;
            acc.x += xv.x * wgt[0][t];
            acc.y += xv.y * wgt[1][t];
            acc.z += xv.z * wgt[2][t];
            acc.w += xv.w * wgt[3][t];
        }
    }
    acc.x = fsilu(acc.x); acc.y = fsilu(acc.y);
    acc.z = fsilu(acc.z); acc.w = fsilu(acc.w);
    size_t off = (((size_t)b * LL) + h * WW + w) * DI + c;
    *(float4*)&u[off] = acc;
    *(ushort4*)&u_bf[off] = make_ushort4(f2bf(acc.x), f2bf(acc.y), f2bf(acc.z), f2bf(acc.w));
}

// ---------------------------------------------------------------------------
// post_proj: one wave per row.
// ---------------------------------------------------------------------------
__global__ __launch_bounds__(256) void post_proj(
    const float* __restrict__ xdbl, const float* __restrict__ prompt,
    const float* __restrict__ Wdt, const float* __restrict__ b_dt,
    const float* __restrict__ Wp,
    float* __restrict__ delta, float* __restrict__ Csv)
{
    const int wid = threadIdx.x >> 6, lane = threadIdx.x & 63;
    const int row = blockIdx.x * 4 + wid;

    const float4* dp = (const float4*)&xdbl[(size_t)row * XDS];
    const float4 d0 = dp[0], d1 = dp[1], d2 = dp[2];
    const float dtr[RK] = {d0.x, d0.y, d0.z, d0.w, d1.x, d1.y, d1.z, d1.w,
                           d2.x, d2.y, d2.z, d2.w};

    const int n16 = lane & 15, g = lane >> 4;
    const float* prow = prompt + (size_t)row * DM + g * 48;
    float pw = 0.f;
    #pragma unroll
    for (int cc = 0; cc < 48; cc += 4) {
        const float4 p4 = *(const float4*)&prow[cc];
        const int c = g * 48 + cc;
        pw += p4.x * Wp[(c    ) * NS + n16];
        pw += p4.y * Wp[(c + 1) * NS + n16];
        pw += p4.z * Wp[(c + 2) * NS + n16];
        pw += p4.w * Wp[(c + 3) * NS + n16];
    }
    pw += __shfl_xor(pw, 16);
    pw += __shfl_xor(pw, 32);
    if (lane < 16)
        Csv[(size_t)row * NS + lane] = xdbl[(size_t)row * XDS + 28 + lane] + pw;

    #pragma unroll
    for (int jj = 0; jj < 6; ++jj) {
        int dch = jj * 64 + lane;
        float acc = b_dt[dch];
        #pragma unroll
        for (int r = 0; r < RK; ++r) acc += dtr[r] * Wdt[r * DI + dch];
        delta[(size_t)row * DI + dch] = (acc > 20.f) ? acc : log1pf(__expf(acc));
    }
}

// ---------------------------------------------------------------------------
// Scan phase 1 v3: thread per (b,chunk,d), 16 n-states in registers,
// 1-deep register prefetch of next step's (delta, u, Bs), native exp2.
// ---------------------------------------------------------------------------
__global__ __launch_bounds__(256) void scan_p1_v3(
    const float* __restrict__ delta, const float* __restrict__ u,
    const float* __restrict__ xdbl, const float* __restrict__ A_log,
    float* __restrict__ Aprod, float* __restrict__ Hout)
{
    const int g = blockIdx.x * 256 + threadIdx.x;   // bc*DI + d
    const int d = g % DI;
    const int bc = g / DI;                           // b*NC + c
    const int b = bc / NC, c = bc % NC;

    float Adn[NS], h[NS], ap[NS];
    #pragma unroll
    for (int n = 0; n < NS; ++n) {
        Adn[n] = -__expf(A_log[d * NS + n]) * LOG2E;   // log2(e) folded
        h[n] = 0.f;
        ap[n] = 1.f;
    }
    const size_t rbase = (size_t)(b * LL + c * CH);
    const float* dp = delta + rbase * DI + d;
    const float* up = u     + rbase * DI + d;
    const float* xp = xdbl  + rbase * XDS + 12;   // Bs cols 12..27

    float dlt = dp[0], uu = up[0];
    float4 bb0 = *(const float4*)(xp + 0), bb1 = *(const float4*)(xp + 4);
    float4 bb2 = *(const float4*)(xp + 8), bb3 = *(const float4*)(xp + 12);

    for (int i = 0; i < CH; ++i) {
        // prefetch step i+1 (OOB-by-one on last iter: mapped, unused)
        const float dlt_n = dp[(i + 1) * DI];
        const float uu_n  = up[(i + 1) * DI];
        const float* xn = xp + (i + 1) * XDS;
        const float4 bn0 = *(const float4*)(xn + 0), bn1 = *(const float4*)(xn + 4);
        const float4 bn2 = *(const float4*)(xn + 8), bn3 = *(const float4*)(xn + 12);

        const float du = dlt * uu;
        const float bs[NS] = {bb0.x, bb0.y, bb0.z, bb0.w, bb1.x, bb1.y, bb1.z, bb1.w,
                              bb2.x, bb2.y, bb2.z, bb2.w, bb3.x, bb3.y, bb3.z, bb3.w};
        #pragma unroll
        for (int n = 0; n < NS; ++n) {
            const float a = fexp2(dlt * Adn[n]);
            h[n] = a * h[n] + du * bs[n];
            ap[n] *= a;
        }
        dlt = dlt_n; uu = uu_n;
        bb0 = bn0; bb1 = bn1; bb2 = bn2; bb3 = bn3;
    }
    const size_t idx = ((size_t)bc * DI + d) * NS;
    #pragma unroll
    for (int q = 0; q < 4; ++q) {
        *(float4*)&Aprod[idx + q * 4] =
            make_float4(ap[q*4], ap[q*4+1], ap[q*4+2], ap[q*4+3]);
        *(float4*)&Hout[idx + q * 4] =
            make_float4(h[q*4], h[q*4+1], h[q*4+2], h[q*4+3]);
    }
}

// ---------------------------------------------------------------------------
// Scan phase 2: sequential over chunks per (b,d,n), 1-deep prefetch.
// Writes chunk-entry state IN-PLACE over Aprod.
// ---------------------------------------------------------------------------
__global__ __launch_bounds__(256) void scan_p2(
    float* __restrict__ Aprod, const float* __restrict__ Hout)
{
    const int gid = blockIdx.x * 256 + threadIdx.x;   // (b*DI + d)*NS + n
    const int dn = gid % (DI * NS);
    const int b  = gid / (DI * NS);
    const size_t base = (size_t)b * NC * DI * NS + dn;
    const size_t cstride = (size_t)DI * NS;

    float hin = 0.f;
    float ap = Aprod[base], ho = Hout[base];
    for (int c = 0; c < NC; ++c) {
        const size_t idx = base + (size_t)c * cstride;
        const float ap_n = Aprod[idx + cstride];   // OOB-by-one on last: mapped
        const float ho_n = Hout[idx + cstride];
        Aprod[idx] = hin;          // becomes Hin
        hin = ap * hin + ho;
        ap = ap_n; ho = ho_n;
    }
}

// ---------------------------------------------------------------------------
// Scan phase 3 + LayerNorm + SiLU(z) gate, fused — v2: ONE barrier.
// Phase A (unrolled): scan all CH steps, acc[i] in registers; per-wave shfl
// partials of (s, sq) written to per-wave LDS slots (no barrier).
// One __syncthreads. Phase B (unrolled): combine 6 wave-partials per step
// (wave-uniform LDS broadcast), normalize, gate with SiLU(z), emit bf16.
// ---------------------------------------------------------------------------
__global__ __launch_bounds__(384) void scan_p3_ln(
    const float* __restrict__ delta, const float* __restrict__ u,
    const float* __restrict__ xdbl, const float* __restrict__ Csv,
    const float* __restrict__ Hin, const float* __restrict__ A_log,
    const float* __restrict__ Dvec, const float* __restrict__ z,
    const float* __restrict__ ln_g, const float* __restrict__ ln_b,
    unsigned short* __restrict__ yin_bf)
{
    __shared__ float red_s[CH][8], red_sq[CH][8];   // [step][wave], 2 KB
    const int d = threadIdx.x;                 // 0..383
    const int bc = blockIdx.x;                 // b*NC + c
    const int b = bc / NC, c = bc % NC;
    const int wid = d >> 6, lane = d & 63;

    float Adn[NS], h[NS];
    #pragma unroll
    for (int n = 0; n < NS; ++n)
        Adn[n] = -__expf(A_log[d * NS + n]) * LOG2E;
    {
        const size_t idx = ((size_t)bc * DI + d) * NS;
        #pragma unroll
        for (int q = 0; q < 4; ++q) {
            const float4 hv = *(const float4*)&Hin[idx + q * 4];
            h[q*4] = hv.x; h[q*4+1] = hv.y; h[q*4+2] = hv.z; h[q*4+3] = hv.w;
        }
    }
    const float Dd = Dvec[d];
    const float lg = ln_g[d], lb = ln_b[d];

    const size_t rbase = (size_t)(b * LL + c * CH);
    const float* dp = delta + rbase * DI + d;
    const float* up = u     + rbase * DI + d;
    const float* zp = z     + rbase * DI + d;
    const float* xp = xdbl  + rbase * XDS + 12;
    const float* cp = Csv   + rbase * NS;
    unsigned short* yp = yin_bf + rbase * DI + d;

    float accs[CH];

    // ---- Phase A: scan, no barriers ----
    #pragma unroll
    for (int i = 0; i < CH; ++i) {
        const float dlt = dp[(size_t)i * DI];
        const float uu  = up[(size_t)i * DI];
        const float* xr = xp + (size_t)i * XDS;
        const float* cr = cp + (size_t)i * NS;
        const float4 bb0 = *(const float4*)(xr + 0), bb1 = *(const float4*)(xr + 4);
        const float4 bb2 = *(const float4*)(xr + 8), bb3 = *(const float4*)(xr + 12);
        const float4 cc0 = *(const float4*)(cr + 0), cc1 = *(const float4*)(cr + 4);
        const float4 cc2 = *(const float4*)(cr + 8), cc3 = *(const float4*)(cr + 12);
        const float du = dlt * uu;
        const float bs[NS] = {bb0.x, bb0.y, bb0.z, bb0.w, bb1.x, bb1.y, bb1.z, bb1.w,
                              bb2.x, bb2.y, bb2.z, bb2.w, bb3.x, bb3.y, bb3.z, bb3.w};
        const float cs[NS] = {cc0.x, cc0.y, cc0.z, cc0.w, cc1.x, cc1.y, cc1.z, cc1.w,
                              cc2.x, cc2.y, cc2.z, cc2.w, cc3.x, cc3.y, cc3.z, cc3.w};
        float acc = uu * Dd;
        #pragma unroll
        for (int n = 0; n < NS; ++n) {
            const float a = fexp2(dlt * Adn[n]);
            h[n] = a * h[n] + du * bs[n];
            acc += h[n] * cs[n];
        }
        accs[i] = acc;
        float s = acc, sq = acc * acc;
        #pragma unroll
        for (int m = 1; m < 64; m <<= 1) {
            s  += __shfl_xor(s, m);
            sq += __shfl_xor(sq, m);
        }
        if (lane == 0) { red_s[i][wid] = s; red_sq[i][wid] = sq; }
    }

    __syncthreads();   // the only barrier

    // ---- Phase B: normalize + gate ----
    #pragma unroll
    for (int i = 0; i < CH; ++i) {
        const float s = red_s[i][0] + red_s[i][1] + red_s[i][2]
                      + red_s[i][3] + red_s[i][4] + red_s[i][5];
        const float sq = red_sq[i][0] + red_sq[i][1] + red_sq[i][2]
                       + red_sq[i][3] + red_sq[i][4] + red_sq[i][5];
        const float mu = s * (1.f / DI);
        const float var = sq * (1.f / DI) - mu * mu;
        const float inv = rsqrtf(var + 1e-5f);
        const float zz = zp[(size_t)i * DI];
        const float yn = (accs[i] - mu) * inv * lg + lb;
        yp[(size_t)i * DI] = f2bf(yn * fsilu(zz));
    }
}

// ---------------------------------------------------------------------------
extern "C" void kernel_launch(void* const* d_in, const int* in_sizes, int n_in,
                              void* d_out, int out_size, void* d_ws, size_t ws_size,
                              hipStream_t stream)
{
    const float* x      = (const float*)d_in[0];
    const float* prompt = (const float*)d_in[1];
    const float* W_in   = (const float*)d_in[2];
    const float* conv_w = (const float*)d_in[3];
    const float* conv_b = (const float*)d_in[4];
    const float* Wx     = (const float*)d_in[5];
    const float* Wdt    = (const float*)d_in[6];
    const float* b_dt   = (const float*)d_in[7];
    const float* A_log  = (const float*)d_in[8];
    const float* Dvec   = (const float*)d_in[9];
    const float* Wp     = (const float*)d_in[10];
    const float* ln_g   = (const float*)d_in[11];
    const float* ln_b   = (const float*)d_in[12];
    const float* Wout   = (const float*)d_in[13];
    float* out = (float*)d_out;

    char* ws = (char*)d_ws;
    const size_t SZ_BLD = (size_t)ROWS * DI * 4;   // 25165824 B
    float* xi    = (float*)(ws);
    float* z     = (float*)(ws + SZ_BLD);
    float* u     = (float*)(ws + 2 * SZ_BLD);
    float* delta = (float*)(ws + 3 * SZ_BLD);
    char*  p     = ws + 4 * SZ_BLD;
    unsigned short* x_bf   = (unsigned short*)p;  p += (size_t)ROWS * DM * 2;      // 6.3 MB
    unsigned short* u_bf   = (unsigned short*)p;  p += (size_t)ROWS * DI * 2;      // 12.6 MB
    float* xdbl  = (float*)p;            p += (size_t)ROWS * XDS * 4;              // 4 MB
    float* Csv   = (float*)p;            p += (size_t)ROWS * NS * 4;               // 1 MB
    float* Aprod = (float*)p;            p += (size_t)BB * NC * DI * NS * 4;       // 12.6 MB
    float* Hout  = (float*)p;            p += (size_t)BB * NC * DI * NS * 4;       // 12.6 MB
    unsigned short* WinT   = (unsigned short*)p;  p += (size_t)(2 * DI) * DM * 2;  // 288 KB
    unsigned short* WxPadT = (unsigned short*)p;  p += (size_t)XDS * DI * 2;       // 48 KB
    unsigned short* WoutT  = (unsigned short*)p;  p += (size_t)DM * DI * 2;        // 144 KB
    unsigned short* yin_bf = (unsigned short*)xi; // xi dead after conv

    // 0. bf16 conversions / transposed weight builds
    f32_to_bf16_vec<<<(ROWS * DM / 4 + 255) / 256, 256, 0, stream>>>(x, x_bf, ROWS * DM / 4);
    build_bt<<<(2 * DI * DM + 255) / 256, 256, 0, stream>>>(W_in, WinT, DM, 2 * DI, 2 * DI);
    build_bt<<<(XDS * DI + 255) / 256, 256, 0, stream>>>(Wx, WxPadT, DI, 44, XDS);
    build_bt<<<(DM * DI + 255) / 256, 256, 0, stream>>>(Wout, WoutT, DI, DM, DM);

    // 1. xz = x @ W_in, split -> xi, z   (M=16384, N=768, K=192)
    {
        dim3 g(ROWS / 64, (2 * DI) / 64);
        gemm_bf16_mfma<true><<<g, 256, 0, stream>>>(x_bf, WinT, xi, z, ROWS, 2 * DI, DM, DI);
    }
    // 2. depthwise conv + bias + SiLU -> u (f32) + u_bf (bf16)
    conv_dw_silu<<<(BB * HH * WW * 96) / 256, 256, 0, stream>>>(xi, conv_w, conv_b, u, u_bf);
    // 3a. xdbl = u @ WxPad  (M=16384, N=64, K=384)
    {
        dim3 g(ROWS / 64, 1);
        gemm_bf16_mfma<false><<<g, 256, 0, stream>>>(u_bf, WxPadT, xdbl, nullptr, ROWS, XDS, DI, 0);
    }
    // 3b. Cs (+prompt@Wp) and delta (softplus low-rank)
    post_proj<<<ROWS / 4, 256, 0, stream>>>(xdbl, prompt, Wdt, b_dt, Wp, delta, Csv);
    // 4-6. chunked selective scan (p2 writes Hin in-place over Aprod)
    scan_p1_v3<<<(BB * NC * DI) / 256, 256, 0, stream>>>(delta, u, xdbl, A_log, Aprod, Hout);
    scan_p2<<<(BB * DI * NS) / 256, 256, 0, stream>>>(Aprod, Hout);
    // 7. scan replay + LayerNorm + SiLU(z) gate -> yin_bf (reuses xi)
    scan_p3_ln<<<BB * NC, 384, 0, stream>>>(delta, u, xdbl, Csv, Aprod, A_log,
                                            Dvec, z, ln_g, ln_b, yin_bf);
    // 8. out = yin @ Wout  (M=16384, N=192, K=384)
    {
        dim3 g(ROWS / 64, DM / 64);
        gemm_bf16_mfma<false><<<g, 256, 0, stream>>>(yin_bf, WoutT, out, nullptr, ROWS, DM, DI, 0);
    }
}

// Round 8
// 290.048 us; speedup vs baseline: 1.0007x; 1.0007x over previous
//
#include <hip/hip_runtime.h>
#include <hip/hip_bf16.h>

// Problem constants
#define BB 4
#define HH 64
#define WW 64
#define LL 4096           // HH*WW
#define DM 192            // D_MODEL
#define DI 384            // D_INNER
#define NS 16             // D_STATE
#define RK 12             // DT_RANK
#define NC 256            // number of scan chunks
#define CH 16             // chunk length (NC*CH == LL)
#define ROWS 16384        // BB*LL
#define XDS 64            // xdbl row stride (44 cols padded to 64)
#define LOG2E 1.44269504f

typedef __bf16 bf16x8 __attribute__((ext_vector_type(8)));
typedef float  f32x4  __attribute__((ext_vector_type(4)));

#if defined(__has_builtin)
#if __has_builtin(__builtin_amdgcn_exp2f)
#define fexp2(x) __builtin_amdgcn_exp2f(x)
#else
#define fexp2(x) exp2f(x)
#endif
#else
#define fexp2(x) exp2f(x)
#endif

__device__ __forceinline__ float fsilu(float x) {
    return x / (1.0f + __expf(-x));
}

// f32 -> bf16 (RNE)
__device__ __forceinline__ unsigned short f2bf(float f) {
    unsigned int u = __float_as_uint(f);
    unsigned int r = (u + 0x7fffu + ((u >> 16) & 1u)) >> 16;
    return (unsigned short)r;
}

// ---------------------------------------------------------------------------
// Vectorized f32 -> bf16 convert (n multiple of 4)
// ---------------------------------------------------------------------------
__global__ __launch_bounds__(256) void f32_to_bf16_vec(
    const float* __restrict__ src, unsigned short* __restrict__ dst, int n4)
{
    int i = blockIdx.x * 256 + threadIdx.x;
    if (i < n4) {
        float4 v = ((const float4*)src)[i];
        ((ushort4*)dst)[i] = make_ushort4(f2bf(v.x), f2bf(v.y), f2bf(v.z), f2bf(v.w));
    }
}

// ---------------------------------------------------------------------------
// Build transposed bf16 weight: src (K x Nsrc f32) -> dst (Nrows x K bf16),
// rows n >= Nsrc are zero (padding).
// ---------------------------------------------------------------------------
__global__ __launch_bounds__(256) void build_bt(
    const float* __restrict__ src, unsigned short* __restrict__ dst,
    int K, int Nsrc, int Nrows)
{
    int idx = blockIdx.x * 256 + threadIdx.x;
    if (idx >= Nrows * K) return;
    int n = idx / K, k = idx % K;
    dst[idx] = (n < Nsrc) ? f2bf(src[k * Nsrc + n]) : (unsigned short)0;
}

// ---------------------------------------------------------------------------
// bf16 MFMA GEMM: C(MxN f32) = A(MxK bf16) * BT^T (BT is N x K bf16).
// 64x64 tile, BK=32. 256 thr = 4 waves (2x2), each wave 32x32 via 2x2
// mfma_f32_16x16x32_bf16 fragments. LDS row stride 80B (2-way bank alias).
// ---------------------------------------------------------------------------
template<bool SPLIT>
__global__ __launch_bounds__(256) void gemm_bf16_mfma(
    const unsigned short* __restrict__ A, const unsigned short* __restrict__ BT,
    float* __restrict__ C0, float* __restrict__ C1,
    int M, int N, int K, int halfN)
{
    __shared__ __align__(16) char lds[64 * 80 * 2];
    char* As = lds;
    char* Bs = lds + 64 * 80;
    const int tid = threadIdx.x;
    const int w = tid >> 6, lane = tid & 63;
    const int wm = w >> 1, wn = w & 1;
    const int row0 = blockIdx.x * 64, col0 = blockIdx.y * 64;
    const int r = tid >> 2, cch = tid & 3;
    const int l15 = lane & 15, k8 = lane >> 4;

    f32x4 acc[2][2] = {};
    for (int k0 = 0; k0 < K; k0 += 32) {
        *(float4*)(As + r * 80 + cch * 16) =
            *(const float4*)(A + (size_t)(row0 + r) * K + k0 + cch * 8);
        *(float4*)(Bs + r * 80 + cch * 16) =
            *(const float4*)(BT + (size_t)(col0 + r) * K + k0 + cch * 8);
        __syncthreads();
        bf16x8 a0 = *(const bf16x8*)(As + (wm * 32 +      l15) * 80 + k8 * 16);
        bf16x8 a1 = *(const bf16x8*)(As + (wm * 32 + 16 + l15) * 80 + k8 * 16);
        bf16x8 b0 = *(const bf16x8*)(Bs + (wn * 32 +      l15) * 80 + k8 * 16);
        bf16x8 b1 = *(const bf16x8*)(Bs + (wn * 32 + 16 + l15) * 80 + k8 * 16);
        acc[0][0] = __builtin_amdgcn_mfma_f32_16x16x32_bf16(a0, b0, acc[0][0], 0, 0, 0);
        acc[0][1] = __builtin_amdgcn_mfma_f32_16x16x32_bf16(a0, b1, acc[0][1], 0, 0, 0);
        acc[1][0] = __builtin_amdgcn_mfma_f32_16x16x32_bf16(a1, b0, acc[1][0], 0, 0, 0);
        acc[1][1] = __builtin_amdgcn_mfma_f32_16x16x32_bf16(a1, b1, acc[1][1], 0, 0, 0);
        __syncthreads();
    }

    float* Cw;
    int cbase, cstride;
    if (SPLIT) {
        cstride = halfN;
        if (col0 < halfN) { Cw = C0; cbase = col0; }
        else              { Cw = C1; cbase = col0 - halfN; }
    } else {
        Cw = C0; cbase = col0; cstride = N;
    }
    #pragma unroll
    for (int fm = 0; fm < 2; ++fm)
        #pragma unroll
        for (int fn = 0; fn < 2; ++fn)
            #pragma unroll
            for (int reg = 0; reg < 4; ++reg) {
                int row = row0 + wm * 32 + fm * 16 + k8 * 4 + reg;
                int col = cbase + wn * 32 + fn * 16 + l15;
                Cw[(size_t)row * cstride + col] = acc[fm][fn][reg];
            }
}

// ---------------------------------------------------------------------------
// Depthwise 3x3 conv (channel-last), bias + SiLU -> u (f32) + u_bf (bf16)
// ---------------------------------------------------------------------------
__global__ __launch_bounds__(256) void conv_dw_silu(
    const float* __restrict__ xi, const float* __restrict__ conv_w,
    const float* __restrict__ conv_b, float* __restrict__ u,
    unsigned short* __restrict__ u_bf)
{
    int idx = blockIdx.x * 256 + threadIdx.x;   // total BB*HH*WW*96
    int c4 = idx % 96;
    int rest = idx / 96;
    int w = rest % WW; rest /= WW;
    int h = rest % HH;
    int b = rest / HH;
    int c = c4 * 4;

    float wgt[4][9];
    #pragma unroll
    for (int q = 0; q < 4; ++q)
        #pragma unroll
        for (int t = 0; t < 9; ++t)
            wgt[q][t] = conv_w[(c + q) * 9 + t];

    float4 acc = *(const float4*)&conv_b[c];
    #pragma unroll
    for (int kh = 0; kh < 3; ++kh) {
        int hh = h + kh - 1;
        if ((unsigned)hh >= HH) continue;
        #pragma unroll
        for (int kw = 0; kw < 3; ++kw) {
            int ww = w + kw - 1;
            if ((unsigned)ww >= WW) continue;
            const float4 xv = *(const float4*)&xi[(((size_t)(b * HH + hh)) * WW + ww) * DI + c];
            int t = kh * 3 + kw;
            acc.x += xv.x * wgt[0][t];
            acc.y += xv.y * wgt[1][t];
            acc.z += xv.z * wgt[2][t];
            acc.w += xv.w * wgt[3][t];
        }
    }
    acc.x = fsilu(acc.x); acc.y = fsilu(acc.y);
    acc.z = fsilu(acc.z); acc.w = fsilu(acc.w);
    size_t off = (((size_t)b * LL) + h * WW + w) * DI + c;
    *(float4*)&u[off] = acc;
    *(ushort4*)&u_bf[off] = make_ushort4(f2bf(acc.x), f2bf(acc.y), f2bf(acc.z), f2bf(acc.w));
}

// ---------------------------------------------------------------------------
// post_proj: one wave per row.
// ---------------------------------------------------------------------------
__global__ __launch_bounds__(256) void post_proj(
    const float* __restrict__ xdbl, const float* __restrict__ prompt,
    const float* __restrict__ Wdt, const float* __restrict__ b_dt,
    const float* __restrict__ Wp,
    float* __restrict__ delta, float* __restrict__ Csv)
{
    const int wid = threadIdx.x >> 6, lane = threadIdx.x & 63;
    const int row = blockIdx.x * 4 + wid;

    const float4* dp = (const float4*)&xdbl[(size_t)row * XDS];
    const float4 d0 = dp[0], d1 = dp[1], d2 = dp[2];
    const float dtr[RK] = {d0.x, d0.y, d0.z, d0.w, d1.x, d1.y, d1.z, d1.w,
                           d2.x, d2.y, d2.z, d2.w};

    const int n16 = lane & 15, g = lane >> 4;
    const float* prow = prompt + (size_t)row * DM + g * 48;
    float pw = 0.f;
    #pragma unroll
    for (int cc = 0; cc < 48; cc += 4) {
        const float4 p4 = *(const float4*)&prow[cc];
        const int c = g * 48 + cc;
        pw += p4.x * Wp[(c    ) * NS + n16];
        pw += p4.y * Wp[(c + 1) * NS + n16];
        pw += p4.z * Wp[(c + 2) * NS + n16];
        pw += p4.w * Wp[(c + 3) * NS + n16];
    }
    pw += __shfl_xor(pw, 16);
    pw += __shfl_xor(pw, 32);
    if (lane < 16)
        Csv[(size_t)row * NS + lane] = xdbl[(size_t)row * XDS + 28 + lane] + pw;

    #pragma unroll
    for (int jj = 0; jj < 6; ++jj) {
        int dch = jj * 64 + lane;
        float acc = b_dt[dch];
        #pragma unroll
        for (int r = 0; r < RK; ++r) acc += dtr[r] * Wdt[r * DI + dch];
        delta[(size_t)row * DI + dch] = (acc > 20.f) ? acc : log1pf(__expf(acc));
    }
}

// ---------------------------------------------------------------------------
// Scan phase 1 v4: thread per (b,chunk,d), 16 n-states in registers,
// 1-deep prefetch, native exp2.  ap computed as exp2(Adn * sum(delta))
// (product-of-exp identity) -> 1 add/step instead of 16 muls.
// Writes interleaved AH pairs {ap, h}.
// ---------------------------------------------------------------------------
__global__ __launch_bounds__(256) void scan_p1_v4(
    const float* __restrict__ delta, const float* __restrict__ u,
    const float* __restrict__ xdbl, const float* __restrict__ A_log,
    float* __restrict__ AH)
{
    const int g = blockIdx.x * 256 + threadIdx.x;   // bc*DI + d
    const int d = g % DI;
    const int bc = g / DI;                           // b*NC + c
    const int b = bc / NC, c = bc % NC;

    float Adn[NS], h[NS];
    {
        const float4* ap4 = (const float4*)(A_log + d * NS);
        #pragma unroll
        for (int q = 0; q < 4; ++q) {
            const float4 v = ap4[q];
            Adn[q*4+0] = -__expf(v.x) * LOG2E;
            Adn[q*4+1] = -__expf(v.y) * LOG2E;
            Adn[q*4+2] = -__expf(v.z) * LOG2E;
            Adn[q*4+3] = -__expf(v.w) * LOG2E;
        }
    }
    #pragma unroll
    for (int n = 0; n < NS; ++n) h[n] = 0.f;

    const size_t rbase = (size_t)(b * LL + c * CH);
    const float* dp = delta + rbase * DI + d;
    const float* up = u     + rbase * DI + d;
    const float* xp = xdbl  + rbase * XDS + 12;   // Bs cols 12..27

    float dlt = dp[0], uu = up[0];
    float4 bb0 = *(const float4*)(xp + 0), bb1 = *(const float4*)(xp + 4);
    float4 bb2 = *(const float4*)(xp + 8), bb3 = *(const float4*)(xp + 12);
    float sdlt = 0.f;

    for (int i = 0; i < CH; ++i) {
        // prefetch step i+1 (OOB-by-one on last iter: mapped, unused)
        const float dlt_n = dp[(i + 1) * DI];
        const float uu_n  = up[(i + 1) * DI];
        const float* xn = xp + (i + 1) * XDS;
        const float4 bn0 = *(const float4*)(xn + 0), bn1 = *(const float4*)(xn + 4);
        const float4 bn2 = *(const float4*)(xn + 8), bn3 = *(const float4*)(xn + 12);

        const float du = dlt * uu;
        sdlt += dlt;
        const float bs[NS] = {bb0.x, bb0.y, bb0.z, bb0.w, bb1.x, bb1.y, bb1.z, bb1.w,
                              bb2.x, bb2.y, bb2.z, bb2.w, bb3.x, bb3.y, bb3.z, bb3.w};
        #pragma unroll
        for (int n = 0; n < NS; ++n) {
            const float a = fexp2(dlt * Adn[n]);
            h[n] = a * h[n] + du * bs[n];
        }
        dlt = dlt_n; uu = uu_n;
        bb0 = bn0; bb1 = bn1; bb2 = bn2; bb3 = bn3;
    }
    // AH[k] = {ap[k], h[k]} interleaved floats at base 2*((bc*DI+d)*NS)
    float* dst = AH + 2 * (((size_t)bc * DI + d) * NS);
    #pragma unroll
    for (int q = 0; q < 8; ++q) {
        const float ap0 = fexp2(sdlt * Adn[2*q]);
        const float ap1 = fexp2(sdlt * Adn[2*q+1]);
        *(float4*)(dst + 4 * q) = make_float4(ap0, h[2*q], ap1, h[2*q+1]);
    }
}

// ---------------------------------------------------------------------------
// Scan phase 2: sequential over NC chunks per (b,d,n) chain, 4-deep prefetch
// on interleaved float2 AH.  Writes chunk-entry state into AH[].x in-place.
// ---------------------------------------------------------------------------
__global__ __launch_bounds__(256) void scan_p2(float2* __restrict__ AH)
{
    const int gid = blockIdx.x * 256 + threadIdx.x;   // (b*DI + d)*NS + n
    const int dn = gid % (DI * NS);
    const int b  = gid / (DI * NS);
    const size_t base = (size_t)b * NC * DI * NS + dn;
    const size_t cs = (size_t)DI * NS;

    float2 buf[4];
    #pragma unroll
    for (int k = 0; k < 4; ++k) buf[k] = AH[base + (size_t)k * cs];

    float hin = 0.f;
    for (int c = 0; c < NC; c += 4) {
        #pragma unroll
        for (int k = 0; k < 4; ++k) {
            const int cn = (c + k + 4 < NC) ? (c + k + 4) : (NC - 1);  // clamp
            const float2 nxt = AH[base + (size_t)cn * cs];
            const float2 cur = buf[k];
            AH[base + (size_t)(c + k) * cs].x = hin;   // becomes Hin
            hin = cur.x * hin + cur.y;
            buf[k] = nxt;
        }
    }
}

// ---------------------------------------------------------------------------
// Scan phase 3 + LayerNorm + SiLU(z) gate, fused (R6 rolling shape, CH=16).
// Hin read from AH[].x.
// ---------------------------------------------------------------------------
__global__ __launch_bounds__(384) void scan_p3_ln(
    const float* __restrict__ delta, const float* __restrict__ u,
    const float* __restrict__ xdbl, const float* __restrict__ Csv,
    const float* __restrict__ AH, const float* __restrict__ A_log,
    const float* __restrict__ Dvec, const float* __restrict__ z,
    const float* __restrict__ ln_g, const float* __restrict__ ln_b,
    unsigned short* __restrict__ yin_bf)
{
    __shared__ float red_s[2][8], red_sq[2][8];
    const int d = threadIdx.x;                 // 0..383
    const int bc = blockIdx.x;                 // b*NC + c
    const int b = bc / NC, c = bc % NC;
    const int wid = d >> 6, lane = d & 63;

    float Adn[NS], h[NS];
    {
        const float4* ap4 = (const float4*)(A_log + d * NS);
        #pragma unroll
        for (int q = 0; q < 4; ++q) {
            const float4 v = ap4[q];
            Adn[q*4+0] = -__expf(v.x) * LOG2E;
            Adn[q*4+1] = -__expf(v.y) * LOG2E;
            Adn[q*4+2] = -__expf(v.z) * LOG2E;
            Adn[q*4+3] = -__expf(v.w) * LOG2E;
        }
    }
    {
        const float* hp = AH + 2 * (((size_t)bc * DI + d) * NS);
        #pragma unroll
        for (int q = 0; q < 8; ++q) {
            const float4 v = *(const float4*)(hp + 4 * q);
            h[2*q] = v.x; h[2*q+1] = v.z;      // .x slots hold Hin
        }
    }
    const float Dd = Dvec[d];
    const float lg = ln_g[d], lb = ln_b[d];

    const size_t rbase = (size_t)(b * LL + c * CH);
    const float* dp = delta + rbase * DI + d;
    const float* up = u     + rbase * DI + d;
    const float* zp = z     + rbase * DI + d;
    const float* xp = xdbl  + rbase * XDS + 12;
    const float* cp = Csv   + rbase * NS;
    unsigned short* yp = yin_bf + rbase * DI + d;

    float dlt = dp[0], uu = up[0], zz = zp[0];
    float4 bb0 = *(const float4*)(xp + 0), bb1 = *(const float4*)(xp + 4);
    float4 bb2 = *(const float4*)(xp + 8), bb3 = *(const float4*)(xp + 12);
    float4 cc0 = *(const float4*)(cp + 0), cc1 = *(const float4*)(cp + 4);
    float4 cc2 = *(const float4*)(cp + 8), cc3 = *(const float4*)(cp + 12);

    for (int i = 0; i < CH; ++i) {
        // prefetch step i+1 (OOB-by-one on last iter: mapped, unused)
        const float dlt_n = dp[(i + 1) * DI];
        const float uu_n  = up[(i + 1) * DI];
        const float zz_n  = zp[(i + 1) * DI];
        const float* xn = xp + (i + 1) * XDS;
        const float* cn = cp + (i + 1) * NS;
        const float4 bn0 = *(const float4*)(xn + 0), bn1 = *(const float4*)(xn + 4);
        const float4 bn2 = *(const float4*)(xn + 8), bn3 = *(const float4*)(xn + 12);
        const float4 cn0 = *(const float4*)(cn + 0), cn1 = *(const float4*)(cn + 4);
        const float4 cn2 = *(const float4*)(cn + 8), cn3 = *(const float4*)(cn + 12);

        const float du = dlt * uu;
        const float bs[NS] = {bb0.x, bb0.y, bb0.z, bb0.w, bb1.x, bb1.y, bb1.z, bb1.w,
                              bb2.x, bb2.y, bb2.z, bb2.w, bb3.x, bb3.y, bb3.z, bb3.w};
        const float cs[NS] = {cc0.x, cc0.y, cc0.z, cc0.w, cc1.x, cc1.y, cc1.z, cc1.w,
                              cc2.x, cc2.y, cc2.z, cc2.w, cc3.x, cc3.y, cc3.z, cc3.w};
        float acc = uu * Dd;
        #pragma unroll
        for (int n = 0; n < NS; ++n) {
            const float a = fexp2(dlt * Adn[n]);
            h[n] = a * h[n] + du * bs[n];
            acc += h[n] * cs[n];
        }
        // block LayerNorm reduce over 384 d's (parity LDS double-buffer)
        float s = acc, sq = acc * acc;
        #pragma unroll
        for (int m = 1; m < 64; m <<= 1) {
            s  += __shfl_xor(s, m);
            sq += __shfl_xor(sq, m);
        }
        const int par = i & 1;
        if (lane == 0) { red_s[par][wid] = s; red_sq[par][wid] = sq; }
        __syncthreads();
        s = red_s[par][0] + red_s[par][1] + red_s[par][2]
          + red_s[par][3] + red_s[par][4] + red_s[par][5];
        sq = red_sq[par][0] + red_sq[par][1] + red_sq[par][2]
           + red_sq[par][3] + red_sq[par][4] + red_sq[par][5];
        const float mu = s * (1.f / DI);
        const float var = sq * (1.f / DI) - mu * mu;
        const float inv = rsqrtf(var + 1e-5f);
        const float yn = (acc - mu) * inv * lg + lb;
        yp[(size_t)i * DI] = f2bf(yn * fsilu(zz));

        dlt = dlt_n; uu = uu_n; zz = zz_n;
        bb0 = bn0; bb1 = bn1; bb2 = bn2; bb3 = bn3;
        cc0 = cn0; cc1 = cn1; cc2 = cn2; cc3 = cn3;
    }
}

// ---------------------------------------------------------------------------
extern "C" void kernel_launch(void* const* d_in, const int* in_sizes, int n_in,
                              void* d_out, int out_size, void* d_ws, size_t ws_size,
                              hipStream_t stream)
{
    const float* x      = (const float*)d_in[0];
    const float* prompt = (const float*)d_in[1];
    const float* W_in   = (const float*)d_in[2];
    const float* conv_w = (const float*)d_in[3];
    const float* conv_b = (const float*)d_in[4];
    const float* Wx     = (const float*)d_in[5];
    const float* Wdt    = (const float*)d_in[6];
    const float* b_dt   = (const float*)d_in[7];
    const float* A_log  = (const float*)d_in[8];
    const float* Dvec   = (const float*)d_in[9];
    const float* Wp     = (const float*)d_in[10];
    const float* ln_g   = (const float*)d_in[11];
    const float* ln_b   = (const float*)d_in[12];
    const float* Wout   = (const float*)d_in[13];
    float* out = (float*)d_out;

    char* ws = (char*)d_ws;
    const size_t SZ_BLD = (size_t)ROWS * DI * 4;   // 25165824 B
    float* xi    = (float*)(ws);
    float* z     = (float*)(ws + SZ_BLD);
    float* u     = (float*)(ws + 2 * SZ_BLD);
    float* delta = (float*)(ws + 3 * SZ_BLD);
    char*  p     = ws + 4 * SZ_BLD;
    float* xdbl  = (float*)p;            p += (size_t)ROWS * XDS * 4;              // 4 MB
    float* Csv   = (float*)p;            p += (size_t)ROWS * NS * 4;               // 1 MB
    char*  ahreg = p;
    float* AH    = (float*)p;            p += (size_t)BB * NC * DI * NS * 8;       // 50.3 MB
    unsigned short* WinT   = (unsigned short*)p;  p += (size_t)(2 * DI) * DM * 2;  // 288 KB
    unsigned short* WxPadT = (unsigned short*)p;  p += (size_t)XDS * DI * 2;       // 48 KB
    unsigned short* WoutT  = (unsigned short*)p;  p += (size_t)DM * DI * 2;        // 144 KB
    // x_bf / u_bf live INSIDE the AH region (both dead before scan_p1 writes AH)
    unsigned short* x_bf   = (unsigned short*)ahreg;                               // 6.3 MB
    unsigned short* u_bf   = (unsigned short*)(ahreg + (size_t)ROWS * DM * 2);     // 12.6 MB
    unsigned short* yin_bf = (unsigned short*)xi;  // xi dead after conv

    // 0. bf16 conversions / transposed weight builds
    f32_to_bf16_vec<<<(ROWS * DM / 4 + 255) / 256, 256, 0, stream>>>(x, x_bf, ROWS * DM / 4);
    build_bt<<<(2 * DI * DM + 255) / 256, 256, 0, stream>>>(W_in, WinT, DM, 2 * DI, 2 * DI);
    build_bt<<<(XDS * DI + 255) / 256, 256, 0, stream>>>(Wx, WxPadT, DI, 44, XDS);
    build_bt<<<(DM * DI + 255) / 256, 256, 0, stream>>>(Wout, WoutT, DI, DM, DM);

    // 1. xz = x @ W_in, split -> xi, z   (M=16384, N=768, K=192)
    {
        dim3 g(ROWS / 64, (2 * DI) / 64);
        gemm_bf16_mfma<true><<<g, 256, 0, stream>>>(x_bf, WinT, xi, z, ROWS, 2 * DI, DM, DI);
    }
    // 2. depthwise conv + bias + SiLU -> u (f32) + u_bf (bf16)
    conv_dw_silu<<<(BB * HH * WW * 96) / 256, 256, 0, stream>>>(xi, conv_w, conv_b, u, u_bf);
    // 3a. xdbl = u @ WxPad  (M=16384, N=64, K=384)
    {
        dim3 g(ROWS / 64, 1);
        gemm_bf16_mfma<false><<<g, 256, 0, stream>>>(u_bf, WxPadT, xdbl, nullptr, ROWS, XDS, DI, 0);
    }
    // 3b. Cs (+prompt@Wp) and delta (softplus low-rank)
    post_proj<<<ROWS / 4, 256, 0, stream>>>(xdbl, prompt, Wdt, b_dt, Wp, delta, Csv);
    // 4-6. chunked selective scan (p2 writes Hin in-place into AH[].x)
    scan_p1_v4<<<(BB * NC * DI) / 256, 256, 0, stream>>>(delta, u, xdbl, A_log, AH);
    scan_p2<<<(BB * DI * NS) / 256, 256, 0, stream>>>((float2*)AH);
    // 7. scan replay + LayerNorm + SiLU(z) gate -> yin_bf (reuses xi)
    scan_p3_ln<<<BB * NC, 384, 0, stream>>>(delta, u, xdbl, Csv, AH, A_log,
                                            Dvec, z, ln_g, ln_b, yin_bf);
    // 8. out = yin @ Wout  (M=16384, N=192, K=384)
    {
        dim3 g(ROWS / 64, DM / 64);
        gemm_bf16_mfma<false><<<g, 256, 0, stream>>>(yin_bf, WoutT, out, nullptr, ROWS, DM, DI, 0);
    }
}

// Round 9
// 279.285 us; speedup vs baseline: 1.0393x; 1.0385x over previous
//
#include <hip/hip_runtime.h>
#include <hip/hip_bf16.h>

// Problem constants
#define BB 4
#define HH 64
#define WW 64
#define LL 4096           // HH*WW
#define DM 192            // D_MODEL
#define DI 384            // D_INNER
#define NS 16             // D_STATE
#define RK 12             // DT_RANK
#define NC 256            // number of scan chunks
#define CH 16             // chunk length (NC*CH == LL)
#define ROWS 16384        // BB*LL
#define XDS 64            // xdbl row stride (44 cols meaningful)
#define KA 576            // fused A' width: 384 u_bf | 192 prompt_bf
#define LOG2E 1.44269504f
#define LN2   0.69314718f

typedef __bf16 bf16x8 __attribute__((ext_vector_type(8)));
typedef float  f32x4  __attribute__((ext_vector_type(4)));

#if defined(__has_builtin)
#if __has_builtin(__builtin_amdgcn_exp2f)
#define fexp2(x) __builtin_amdgcn_exp2f(x)
#else
#define fexp2(x) exp2f(x)
#endif
#else
#define fexp2(x) exp2f(x)
#endif

__device__ __forceinline__ float fsilu(float x) {
    return x / (1.0f + __expf(-x));
}

// f32 -> bf16 (RNE)
__device__ __forceinline__ unsigned short f2bf(float f) {
    unsigned int u = __float_as_uint(f);
    unsigned int r = (u + 0x7fffu + ((u >> 16) & 1u)) >> 16;
    return (unsigned short)r;
}
// bf16 -> f32
__device__ __forceinline__ float bf2f(unsigned short v) {
    return __uint_as_float((unsigned int)v << 16);
}

// ---------------------------------------------------------------------------
// x (ROWS x DM f32) -> x_bf (bf16, contiguous)
// ---------------------------------------------------------------------------
__global__ __launch_bounds__(256) void f32_to_bf16_vec(
    const float* __restrict__ src, unsigned short* __restrict__ dst, int n4)
{
    int i = blockIdx.x * 256 + threadIdx.x;
    if (i < n4) {
        float4 v = ((const float4*)src)[i];
        ((ushort4*)dst)[i] = make_ushort4(f2bf(v.x), f2bf(v.y), f2bf(v.z), f2bf(v.w));
    }
}

// ---------------------------------------------------------------------------
// prompt (ROWS x DM f32) -> Across cols 384..575 (stride KA, bf16)
// ---------------------------------------------------------------------------
__global__ __launch_bounds__(256) void prompt_to_across(
    const float* __restrict__ prompt, unsigned short* __restrict__ Across)
{
    int i4 = blockIdx.x * 256 + threadIdx.x;     // ROWS * 48
    if (i4 >= ROWS * (DM / 4)) return;
    int row = i4 / (DM / 4), c4 = i4 % (DM / 4);
    float4 v = ((const float4*)prompt)[i4];
    *(ushort4*)&Across[(size_t)row * KA + DI + c4 * 4] =
        make_ushort4(f2bf(v.x), f2bf(v.y), f2bf(v.z), f2bf(v.w));
}

// ---------------------------------------------------------------------------
// Build transposed bf16 weight: src (K x Nsrc f32) -> dst (Nrows x K bf16)
// ---------------------------------------------------------------------------
__global__ __launch_bounds__(256) void build_bt(
    const float* __restrict__ src, unsigned short* __restrict__ dst,
    int K, int Nsrc, int Nrows)
{
    int idx = blockIdx.x * 256 + threadIdx.x;
    if (idx >= Nrows * K) return;
    int n = idx / K, k = idx % K;
    dst[idx] = (n < Nsrc) ? f2bf(src[k * Nsrc + n]) : (unsigned short)0;
}

// ---------------------------------------------------------------------------
// Build fused B' (XDS rows x KA cols, transposed N x K):
//   k < 384 : Wx[k][n] for n < 44, else 0
//   k >= 384: Wp[k-384][n-28] for 28 <= n < 44, else 0
// ---------------------------------------------------------------------------
__global__ __launch_bounds__(256) void build_bxt(
    const float* __restrict__ Wx, const float* __restrict__ Wp,
    unsigned short* __restrict__ dst)
{
    int idx = blockIdx.x * 256 + threadIdx.x;    // XDS * KA
    if (idx >= XDS * KA) return;
    int n = idx / KA, k = idx % KA;
    float v = 0.f;
    if (k < DI) { if (n < 44) v = Wx[k * 44 + n]; }
    else        { if (n >= 28 && n < 44) v = Wp[(k - DI) * NS + (n - 28)]; }
    dst[idx] = f2bf(v);
}

// ---------------------------------------------------------------------------
// bf16 MFMA GEMM: C = A(MxK bf16) * BT^T (BT is N x K bf16).  64x64 tile,
// BK=32, 4 waves x (2x2) 16x16x32 fragments, LDS stride 80B.
// SPLIT: cols < halfN -> C0 (f32, stride halfN); cols >= halfN -> C1z (bf16).
// ---------------------------------------------------------------------------
template<bool SPLIT>
__global__ __launch_bounds__(256) void gemm_bf16_mfma(
    const unsigned short* __restrict__ A, const unsigned short* __restrict__ BT,
    float* __restrict__ C0, unsigned short* __restrict__ C1z,
    int M, int N, int K, int halfN)
{
    __shared__ __align__(16) char lds[64 * 80 * 2];
    char* As = lds;
    char* Bs = lds + 64 * 80;
    const int tid = threadIdx.x;
    const int w = tid >> 6, lane = tid & 63;
    const int wm = w >> 1, wn = w & 1;
    const int row0 = blockIdx.x * 64, col0 = blockIdx.y * 64;
    const int r = tid >> 2, cch = tid & 3;
    const int l15 = lane & 15, k8 = lane >> 4;

    f32x4 acc[2][2] = {};
    for (int k0 = 0; k0 < K; k0 += 32) {
        *(float4*)(As + r * 80 + cch * 16) =
            *(const float4*)(A + (size_t)(row0 + r) * K + k0 + cch * 8);
        *(float4*)(Bs + r * 80 + cch * 16) =
            *(const float4*)(BT + (size_t)(col0 + r) * K + k0 + cch * 8);
        __syncthreads();
        bf16x8 a0 = *(const bf16x8*)(As + (wm * 32 +      l15) * 80 + k8 * 16);
        bf16x8 a1 = *(const bf16x8*)(As + (wm * 32 + 16 + l15) * 80 + k8 * 16);
        bf16x8 b0 = *(const bf16x8*)(Bs + (wn * 32 +      l15) * 80 + k8 * 16);
        bf16x8 b1 = *(const bf16x8*)(Bs + (wn * 32 + 16 + l15) * 80 + k8 * 16);
        acc[0][0] = __builtin_amdgcn_mfma_f32_16x16x32_bf16(a0, b0, acc[0][0], 0, 0, 0);
        acc[0][1] = __builtin_amdgcn_mfma_f32_16x16x32_bf16(a0, b1, acc[0][1], 0, 0, 0);
        acc[1][0] = __builtin_amdgcn_mfma_f32_16x16x32_bf16(a1, b0, acc[1][0], 0, 0, 0);
        acc[1][1] = __builtin_amdgcn_mfma_f32_16x16x32_bf16(a1, b1, acc[1][1], 0, 0, 0);
        __syncthreads();
    }

    if (SPLIT && col0 >= halfN) {
        const int cbase = col0 - halfN;
        #pragma unroll
        for (int fm = 0; fm < 2; ++fm)
            #pragma unroll
            for (int fn = 0; fn < 2; ++fn)
                #pragma unroll
                for (int reg = 0; reg < 4; ++reg) {
                    int row = row0 + wm * 32 + fm * 16 + k8 * 4 + reg;
                    int col = cbase + wn * 32 + fn * 16 + l15;
                    C1z[(size_t)row * halfN + col] = f2bf(acc[fm][fn][reg]);
                }
    } else {
        const int cstride = SPLIT ? halfN : N;
        #pragma unroll
        for (int fm = 0; fm < 2; ++fm)
            #pragma unroll
            for (int fn = 0; fn < 2; ++fn)
                #pragma unroll
                for (int reg = 0; reg < 4; ++reg) {
                    int row = row0 + wm * 32 + fm * 16 + k8 * 4 + reg;
                    int col = col0 + wn * 32 + fn * 16 + l15;
                    C0[(size_t)row * cstride + col] = acc[fm][fn][reg];
                }
    }
}

// ---------------------------------------------------------------------------
// Depthwise 3x3 conv (channel-last), bias + SiLU.
// xi (B,H,W,DI f32) -> u_bf (bf16) written into Across cols 0..383 (stride KA)
// ---------------------------------------------------------------------------
__global__ __launch_bounds__(256) void conv_dw_silu(
    const float* __restrict__ xi, const float* __restrict__ conv_w,
    const float* __restrict__ conv_b, unsigned short* __restrict__ Across)
{
    int idx = blockIdx.x * 256 + threadIdx.x;   // total BB*HH*WW*96
    int c4 = idx % 96;
    int rest = idx / 96;
    int w = rest % WW; rest /= WW;
    int h = rest % HH;
    int b = rest / HH;
    int c = c4 * 4;

    float wgt[4][9];
    #pragma unroll
    for (int q = 0; q < 4; ++q)
        #pragma unroll
        for (int t = 0; t < 9; ++t)
            wgt[q][t] = conv_w[(c + q) * 9 + t];

    float4 acc = *(const float4*)&conv_b[c];
    #pragma unroll
    for (int kh = 0; kh < 3; ++kh) {
        int hh = h + kh - 1;
        if ((unsigned)hh >= HH) continue;
        #pragma unroll
        for (int kw = 0; kw < 3; ++kw) {
            int ww = w + kw - 1;
            if ((unsigned)ww >= WW) continue;
            const float4 xv = *(const float4*)&xi[(((size_t)(b * HH + hh)) * WW + ww) * DI + c];
            int t = kh * 3 + kw;
            acc.x += xv.x * wgt[0][t];
            acc.y += xv.y * wgt[1][t];
            acc.z += xv.z * wgt[2][t];
            acc.w += xv.w * wgt[3][t];
        }
    }
    acc.x = fsilu(acc.x); acc.y = fsilu(acc.y);
    acc.z = fsilu(acc.z); acc.w = fsilu(acc.w);
    size_t off = (((size_t)b * LL) + h * WW + w) * KA + c;
    *(ushort4*)&Across[off] = make_ushort4(f2bf(acc.x), f2bf(acc.y), f2bf(acc.z), f2bf(acc.w));
}

// ---------------------------------------------------------------------------
// Scan phase 1 v5: thread per (b,chunk,d), 16 n-states in registers.
// delta recomputed inline from xdbl cols 0..11 (wave-uniform) + Wdt column.
// u read as bf16 from Across.  ap via exp2(Adn * sum(delta)).
// Writes interleaved AH pairs {ap, h}.
// ---------------------------------------------------------------------------
__global__ __launch_bounds__(256) void scan_p1_v5(
    const unsigned short* __restrict__ uA, const float* __restrict__ xdbl,
    const float* __restrict__ A_log, const float* __restrict__ Wdt,
    const float* __restrict__ b_dt, float* __restrict__ AH)
{
    const int g = blockIdx.x * 256 + threadIdx.x;   // bc*DI + d
    const int d = g % DI;
    const int bc = g / DI;                           // b*NC + c
    const int b = bc / NC, c = bc % NC;

    float Adn[NS], h[NS];
    {
        const float4* ap4 = (const float4*)(A_log + d * NS);
        #pragma unroll
        for (int q = 0; q < 4; ++q) {
            const float4 v = ap4[q];
            Adn[q*4+0] = -__expf(v.x) * LOG2E;
            Adn[q*4+1] = -__expf(v.y) * LOG2E;
            Adn[q*4+2] = -__expf(v.z) * LOG2E;
            Adn[q*4+3] = -__expf(v.w) * LOG2E;
        }
    }
    float wdt[RK];
    #pragma unroll
    for (int r = 0; r < RK; ++r) wdt[r] = Wdt[r * DI + d];
    const float bdt = b_dt[d];
    #pragma unroll
    for (int n = 0; n < NS; ++n) h[n] = 0.f;

    const size_t rbase = (size_t)(b * LL + c * CH);
    const unsigned short* up = uA + rbase * KA + d;
    const float* xp = xdbl + rbase * XDS;

    float uu = bf2f(up[0]);
    float4 bb0 = *(const float4*)(xp + 12), bb1 = *(const float4*)(xp + 16);
    float4 bb2 = *(const float4*)(xp + 20), bb3 = *(const float4*)(xp + 24);
    float sdlt = 0.f;

    for (int i = 0; i < CH; ++i) {
        // in-step: dtr (wave-uniform)
        const float* xr = xp + (size_t)i * XDS;
        const float4 t0 = *(const float4*)(xr + 0);
        const float4 t1 = *(const float4*)(xr + 4);
        const float4 t2 = *(const float4*)(xr + 8);
        // prefetch step i+1 (OOB-by-one on last iter: padded, unused)
        const float uu_n = bf2f(up[(size_t)(i + 1) * KA]);
        const float* xn = xp + (size_t)(i + 1) * XDS;
        const float4 bn0 = *(const float4*)(xn + 12), bn1 = *(const float4*)(xn + 16);
        const float4 bn2 = *(const float4*)(xn + 20), bn3 = *(const float4*)(xn + 24);

        // delta = softplus(dtr . wdt + bdt)
        float t = bdt;
        t += t0.x * wdt[0] + t0.y * wdt[1] + t0.z * wdt[2]  + t0.w * wdt[3];
        t += t1.x * wdt[4] + t1.y * wdt[5] + t1.z * wdt[6]  + t1.w * wdt[7];
        t += t2.x * wdt[8] + t2.y * wdt[9] + t2.z * wdt[10] + t2.w * wdt[11];
        const float dlt = (t > 20.f) ? t : LN2 * __log2f(1.f + fexp2(t * LOG2E));

        const float du = dlt * uu;
        sdlt += dlt;
        const float bs[NS] = {bb0.x, bb0.y, bb0.z, bb0.w, bb1.x, bb1.y, bb1.z, bb1.w,
                              bb2.x, bb2.y, bb2.z, bb2.w, bb3.x, bb3.y, bb3.z, bb3.w};
        #pragma unroll
        for (int n = 0; n < NS; ++n) {
            const float a = fexp2(dlt * Adn[n]);
            h[n] = a * h[n] + du * bs[n];
        }
        uu = uu_n;
        bb0 = bn0; bb1 = bn1; bb2 = bn2; bb3 = bn3;
    }
    float* dst = AH + 2 * (((size_t)bc * DI + d) * NS);
    #pragma unroll
    for (int q = 0; q < 8; ++q) {
        const float ap0 = fexp2(sdlt * Adn[2*q]);
        const float ap1 = fexp2(sdlt * Adn[2*q+1]);
        *(float4*)(dst + 4 * q) = make_float4(ap0, h[2*q], ap1, h[2*q+1]);
    }
}

// ---------------------------------------------------------------------------
// Scan phase 2: sequential over NC chunks per (b,d,n) chain, 4-deep prefetch
// on interleaved float2 AH.  Writes chunk-entry state into AH[].x in-place.
// ---------------------------------------------------------------------------
__global__ __launch_bounds__(256) void scan_p2(float2* __restrict__ AH)
{
    const int gid = blockIdx.x * 256 + threadIdx.x;   // (b*DI + d)*NS + n
    const int dn = gid % (DI * NS);
    const int b  = gid / (DI * NS);
    const size_t base = (size_t)b * NC * DI * NS + dn;
    const size_t cs = (size_t)DI * NS;

    float2 buf[4];
    #pragma unroll
    for (int k = 0; k < 4; ++k) buf[k] = AH[base + (size_t)k * cs];

    float hin = 0.f;
    for (int c = 0; c < NC; c += 4) {
        #pragma unroll
        for (int k = 0; k < 4; ++k) {
            const int cn = (c + k + 4 < NC) ? (c + k + 4) : (NC - 1);  // clamp
            const float2 nxt = AH[base + (size_t)cn * cs];
            const float2 cur = buf[k];
            AH[base + (size_t)(c + k) * cs].x = hin;   // becomes Hin
            hin = cur.x * hin + cur.y;
            buf[k] = nxt;
        }
    }
}

// ---------------------------------------------------------------------------
// Scan phase 3 + LayerNorm + SiLU(z) gate, fused.  delta recomputed inline;
// Bs/Cs read from xdbl cols 12..43; u/z read as bf16; writes yin_bf.
// ---------------------------------------------------------------------------
__global__ __launch_bounds__(384) void scan_p3_ln_v3(
    const unsigned short* __restrict__ uA, const unsigned short* __restrict__ z_bf,
    const float* __restrict__ xdbl, const float* __restrict__ AH,
    const float* __restrict__ A_log, const float* __restrict__ Wdt,
    const float* __restrict__ b_dt, const float* __restrict__ Dvec,
    const float* __restrict__ ln_g, const float* __restrict__ ln_b,
    unsigned short* __restrict__ yin_bf)
{
    __shared__ float red_s[2][8], red_sq[2][8];
    const int d = threadIdx.x;                 // 0..383
    const int bc = blockIdx.x;                 // b*NC + c
    const int b = bc / NC, c = bc % NC;
    const int wid = d >> 6, lane = d & 63;

    float Adn[NS], h[NS];
    {
        const float4* ap4 = (const float4*)(A_log + d * NS);
        #pragma unroll
        for (int q = 0; q < 4; ++q) {
            const float4 v = ap4[q];
            Adn[q*4+0] = -__expf(v.x) * LOG2E;
            Adn[q*4+1] = -__expf(v.y) * LOG2E;
            Adn[q*4+2] = -__expf(v.z) * LOG2E;
            Adn[q*4+3] = -__expf(v.w) * LOG2E;
        }
    }
    float wdt[RK];
    #pragma unroll
    for (int r = 0; r < RK; ++r) wdt[r] = Wdt[r * DI + d];
    const float bdt = b_dt[d];
    {
        const float* hp = AH + 2 * (((size_t)bc * DI + d) * NS);
        #pragma unroll
        for (int q = 0; q < 8; ++q) {
            const float4 v = *(const float4*)(hp + 4 * q);
            h[2*q] = v.x; h[2*q+1] = v.z;      // .x slots hold Hin
        }
    }
    const float Dd = Dvec[d];
    const float lg = ln_g[d], lb = ln_b[d];

    const size_t rbase = (size_t)(b * LL + c * CH);
    const unsigned short* up = uA + rbase * KA + d;
    const unsigned short* zp = z_bf + rbase * DI + d;
    const float* xp = xdbl + rbase * XDS;
    unsigned short* yp = yin_bf + rbase * DI + d;

    float uu = bf2f(up[0]), zz = bf2f(zp[0]);
    float4 bb0 = *(const float4*)(xp + 12), bb1 = *(const float4*)(xp + 16);
    float4 bb2 = *(const float4*)(xp + 20), bb3 = *(const float4*)(xp + 24);
    float4 cc0 = *(const float4*)(xp + 28), cc1 = *(const float4*)(xp + 32);
    float4 cc2 = *(const float4*)(xp + 36), cc3 = *(const float4*)(xp + 40);

    for (int i = 0; i < CH; ++i) {
        // in-step: dtr (wave-uniform)
        const float* xr = xp + (size_t)i * XDS;
        const float4 t0 = *(const float4*)(xr + 0);
        const float4 t1 = *(const float4*)(xr + 4);
        const float4 t2 = *(const float4*)(xr + 8);
        // prefetch step i+1 (OOB-by-one on last iter: padded, unused)
        const float uu_n = bf2f(up[(size_t)(i + 1) * KA]);
        const float zz_n = bf2f(zp[(size_t)(i + 1) * DI]);
        const float* xn = xp + (size_t)(i + 1) * XDS;
        const float4 bn0 = *(const float4*)(xn + 12), bn1 = *(const float4*)(xn + 16);
        const float4 bn2 = *(const float4*)(xn + 20), bn3 = *(const float4*)(xn + 24);
        const float4 cn0 = *(const float4*)(xn + 28), cn1 = *(const float4*)(xn + 32);
        const float4 cn2 = *(const float4*)(xn + 36), cn3 = *(const float4*)(xn + 40);

        // delta = softplus(dtr . wdt + bdt)
        float t = bdt;
        t += t0.x * wdt[0] + t0.y * wdt[1] + t0.z * wdt[2]  + t0.w * wdt[3];
        t += t1.x * wdt[4] + t1.y * wdt[5] + t1.z * wdt[6]  + t1.w * wdt[7];
        t += t2.x * wdt[8] + t2.y * wdt[9] + t2.z * wdt[10] + t2.w * wdt[11];
        const float dlt = (t > 20.f) ? t : LN2 * __log2f(1.f + fexp2(t * LOG2E));

        const float du = dlt * uu;
        const float bs[NS] = {bb0.x, bb0.y, bb0.z, bb0.w, bb1.x, bb1.y, bb1.z, bb1.w,
                              bb2.x, bb2.y, bb2.z, bb2.w, bb3.x, bb3.y, bb3.z, bb3.w};
        const float cs[NS] = {cc0.x, cc0.y, cc0.z, cc0.w, cc1.x, cc1.y, cc1.z, cc1.w,
                              cc2.x, cc2.y, cc2.z, cc2.w, cc3.x, cc3.y, cc3.z, cc3.w};
        float acc = uu * Dd;
        #pragma unroll
        for (int n = 0; n < NS; ++n) {
            const float a = fexp2(dlt * Adn[n]);
            h[n] = a * h[n] + du * bs[n];
            acc += h[n] * cs[n];
        }
        // block LayerNorm reduce over 384 d's (parity LDS double-buffer)
        float s = acc, sq = acc * acc;
        #pragma unroll
        for (int m = 1; m < 64; m <<= 1) {
            s  += __shfl_xor(s, m);
            sq += __shfl_xor(sq, m);
        }
        const int par = i & 1;
        if (lane == 0) { red_s[par][wid] = s; red_sq[par][wid] = sq; }
        __syncthreads();
        s = red_s[par][0] + red_s[par][1] + red_s[par][2]
          + red_s[par][3] + red_s[par][4] + red_s[par][5];
        sq = red_sq[par][0] + red_sq[par][1] + red_sq[par][2]
           + red_sq[par][3] + red_sq[par][4] + red_sq[par][5];
        const float mu = s * (1.f / DI);
        const float var = sq * (1.f / DI) - mu * mu;
        const float inv = rsqrtf(var + 1e-5f);
        const float yn = (acc - mu) * inv * lg + lb;
        yp[(size_t)i * DI] = f2bf(yn * fsilu(zz));

        uu = uu_n; zz = zz_n;
        bb0 = bn0; bb1 = bn1; bb2 = bn2; bb3 = bn3;
        cc0 = cn0; cc1 = cn1; cc2 = cn2; cc3 = cn3;
    }
}

// ---------------------------------------------------------------------------
extern "C" void kernel_launch(void* const* d_in, const int* in_sizes, int n_in,
                              void* d_out, int out_size, void* d_ws, size_t ws_size,
                              hipStream_t stream)
{
    const float* x      = (const float*)d_in[0];
    const float* prompt = (const float*)d_in[1];
    const float* W_in   = (const float*)d_in[2];
    const float* conv_w = (const float*)d_in[3];
    const float* conv_b = (const float*)d_in[4];
    const float* Wx     = (const float*)d_in[5];
    const float* Wdt    = (const float*)d_in[6];
    const float* b_dt   = (const float*)d_in[7];
    const float* A_log  = (const float*)d_in[8];
    const float* Dvec   = (const float*)d_in[9];
    const float* Wp     = (const float*)d_in[10];
    const float* ln_g   = (const float*)d_in[11];
    const float* ln_b   = (const float*)d_in[12];
    const float* Wout   = (const float*)d_in[13];
    float* out = (float*)d_out;

    char* p = (char*)d_ws;
    float* xi = (float*)p;                 p += (size_t)ROWS * DI * 4;             // 25.2 MB
    unsigned short* z_bf = (unsigned short*)p;  p += (size_t)(ROWS + 1) * DI * 2;  // 12.6 MB (+1 row pad)
    unsigned short* Across = (unsigned short*)p; p += (size_t)(ROWS + 1) * KA * 2; // 18.9 MB (+1 row pad)
    float* xdbl = (float*)p;               p += (size_t)(ROWS + 1) * XDS * 4;      // 4.2 MB (+1 row pad)
    char* ahreg = p;
    float* AH = (float*)p;                 p += (size_t)BB * NC * DI * NS * 8;     // 50.3 MB
    unsigned short* WinT  = (unsigned short*)p;  p += (size_t)(2 * DI) * DM * 2;   // 288 KB
    unsigned short* BxT   = (unsigned short*)p;  p += (size_t)XDS * KA * 2;        // 72 KB
    unsigned short* WoutT = (unsigned short*)p;  p += (size_t)DM * DI * 2;         // 144 KB
    // x_bf lives inside AH region (dead after gemm1, before scan_p1 writes AH)
    unsigned short* x_bf = (unsigned short*)ahreg;                                 // 6.3 MB
    unsigned short* yin_bf = (unsigned short*)xi;  // xi dead after conv

    // 0. conversions / weight builds (independent)
    f32_to_bf16_vec<<<(ROWS * DM / 4 + 255) / 256, 256, 0, stream>>>(x, x_bf, ROWS * DM / 4);
    prompt_to_across<<<(ROWS * (DM / 4) + 255) / 256, 256, 0, stream>>>(prompt, Across);
    build_bt<<<(2 * DI * DM + 255) / 256, 256, 0, stream>>>(W_in, WinT, DM, 2 * DI, 2 * DI);
    build_bxt<<<(XDS * KA + 255) / 256, 256, 0, stream>>>(Wx, Wp, BxT);
    build_bt<<<(DM * DI + 255) / 256, 256, 0, stream>>>(Wout, WoutT, DI, DM, DM);

    // 1. xz = x @ W_in -> xi (f32) | z_bf (bf16)   (M=16384, N=768, K=192)
    {
        dim3 g(ROWS / 64, (2 * DI) / 64);
        gemm_bf16_mfma<true><<<g, 256, 0, stream>>>(x_bf, WinT, xi, z_bf, ROWS, 2 * DI, DM, DI);
    }
    // 2. depthwise conv + bias + SiLU -> u_bf into Across cols 0..383
    conv_dw_silu<<<(BB * HH * WW * 96) / 256, 256, 0, stream>>>(xi, conv_w, conv_b, Across);
    // 3. xdbl = [u | prompt] @ B'  (M=16384, N=64, K=576; Cs includes prompt@Wp)
    {
        dim3 g(ROWS / 64, 1);
        gemm_bf16_mfma<false><<<g, 256, 0, stream>>>(Across, BxT, xdbl, nullptr, ROWS, XDS, KA, 0);
    }
    // 4-6. chunked selective scan (delta recomputed inline; p2 writes Hin into AH[].x)
    scan_p1_v5<<<(BB * NC * DI) / 256, 256, 0, stream>>>(Across, xdbl, A_log, Wdt, b_dt, AH);
    scan_p2<<<(BB * DI * NS) / 256, 256, 0, stream>>>((float2*)AH);
    // 7. scan replay + LayerNorm + SiLU(z) gate -> yin_bf (reuses xi)
    scan_p3_ln_v3<<<BB * NC, 384, 0, stream>>>(Across, z_bf, xdbl, AH, A_log, Wdt,
                                               b_dt, Dvec, ln_g, ln_b, yin_bf);
    // 8. out = yin @ Wout  (M=16384, N=192, K=384)
    {
        dim3 g(ROWS / 64, DM / 64);
        gemm_bf16_mfma<false><<<g, 256, 0, stream>>>(yin_bf, WoutT, out, nullptr, ROWS, DM, DI, 0);
    }
}